// Round 5
// baseline (1184.655 us; speedup 1.0000x reference)
//
#include <hip/hip_runtime.h>

static constexpr int TPB = 256;

// ==================== edge sort by row (counting sort) ====================
__global__ void hist_kernel(const int* __restrict__ row, int* __restrict__ cnt, int er) {
    int e = blockIdx.x * TPB + threadIdx.x;
    if (e >= er) return;
    atomicAdd(&cnt[row[e]], 1);
}

__global__ void scan1_kernel(const int* __restrict__ cnt, int* __restrict__ base,
                             int* __restrict__ bsum, int n) {
    __shared__ int s[TPB];
    int g = blockIdx.x * TPB + threadIdx.x;
    int v = (g < n) ? cnt[g] : 0;
    s[threadIdx.x] = v;
    __syncthreads();
    for (int off = 1; off < TPB; off <<= 1) {
        int t = (threadIdx.x >= off) ? s[threadIdx.x - off] : 0;
        __syncthreads();
        s[threadIdx.x] += t;
        __syncthreads();
    }
    if (g < n) base[g] = s[threadIdx.x] - v;            // exclusive
    if (threadIdx.x == TPB - 1) bsum[blockIdx.x] = s[threadIdx.x];
}

__global__ void scan2_kernel(int* __restrict__ bsum, int nb) {
    __shared__ int s[TPB];
    int v = (threadIdx.x < nb) ? bsum[threadIdx.x] : 0;
    s[threadIdx.x] = v;
    __syncthreads();
    for (int off = 1; off < TPB; off <<= 1) {
        int t = (threadIdx.x >= off) ? s[threadIdx.x - off] : 0;
        __syncthreads();
        s[threadIdx.x] += t;
        __syncthreads();
    }
    if (threadIdx.x < nb) bsum[threadIdx.x] = s[threadIdx.x] - v;   // exclusive
}

__global__ void scan3_kernel(const int* __restrict__ base, int* __restrict__ ptr,
                             const int* __restrict__ bsum, int n) {
    int g = blockIdx.x * TPB + threadIdx.x;
    if (g >= n) return;
    ptr[g] = base[g] + bsum[g >> 8];
}

__global__ void scatter_kernel(const int* __restrict__ row, const int* __restrict__ col,
                               int* __restrict__ ptr, int* __restrict__ rowp,
                               int* __restrict__ colp, int er) {
    int e = blockIdx.x * TPB + threadIdx.x;
    if (e >= er) return;
    int r = row[e];
    int p = atomicAdd(&ptr[r], 1);
    rowp[p] = r;
    colp[p] = col[e];
}

// ==================== per-node inverse L2 norm ====================
template<int F>
__global__ void norm_kernel(const float* __restrict__ feat, float* __restrict__ inv, int n) {
    constexpr int LPN = (F >= 64) ? 64 : F;
    constexpr int EPL = F / LPN;
    int gid = blockIdx.x * TPB + threadIdx.x;
    int node = gid / LPN;
    int lane = gid % LPN;
    if (node >= n) return;
    const float* fr = feat + (size_t)node * F;
    float s = 0.f;
#pragma unroll
    for (int k = 0; k < EPL; ++k) {
        float v = fr[lane + k * LPN];
        s += v * v;
    }
#pragma unroll
    for (int off = LPN / 2; off > 0; off >>= 1)
        s += __shfl_xor(s, off);
    if (lane == 0) inv[node] = (s > 0.f) ? rsqrtf(s) : 1.0f;
}

// ---- wave-aggregated survivor compaction: 1 atomic per wave ----
__device__ __forceinline__ void compact_push(bool p, int e, float s, int wlane,
                                             int* __restrict__ svlist, float* __restrict__ svs,
                                             int* __restrict__ svcnt) {
    unsigned long long m = __ballot(p);
    if (m == 0ull) return;
    int total = __popcll(m);
    int ldr = __ffsll((long long)m) - 1;
    int base = 0;
    if (wlane == ldr) base = atomicAdd(svcnt, total);
    base = __shfl(base, ldr);
    if (p) {
        int off = __popcll(m & ((1ull << wlane) - 1ull));
        svlist[base + off] = e;
        svs[base + off] = s;
    }
}

// ==================== edge cosine sim over row-sorted random edges; compact survivors ====================
template<int F>
__global__ void sim_kernel(const float* __restrict__ feat, const float* __restrict__ inv,
                           const int* __restrict__ rowp, const int* __restrict__ colp,
                           float* __restrict__ rs, float* __restrict__ deg,
                           int* __restrict__ svlist, float* __restrict__ svs, int* __restrict__ svcnt,
                           long long ne) {
    constexpr int LPE = (F >= 128) ? 16 : (F / 4);
    constexpr int NV  = F / LPE / 4;
    long long half = (ne + 1) >> 1;
    long long gid = (long long)blockIdx.x * TPB + threadIdx.x;
    long long slot = gid / LPE;
    int lane = (int)(gid % LPE);
    int wlane = (int)(threadIdx.x & 63);
    bool active = (slot < half);
    long long e0 = active ? slot : 0;
    long long e1 = slot + half;
    bool has1 = active && (e1 < ne);
    if (!has1) e1 = e0;
    int r0 = active ? rowp[e0] : 0, c0 = active ? colp[e0] : 0;
    int r1 = rowp[e1], c1 = colp[e1];
    float s0 = 0.f, s1 = 0.f;
    if (active) {
        const float4* a0p = (const float4*)(feat + (size_t)r0 * F) + lane * NV;
        const float4* b0p = (const float4*)(feat + (size_t)c0 * F) + lane * NV;
        const float4* a1p = (const float4*)(feat + (size_t)r1 * F) + lane * NV;
        const float4* b1p = (const float4*)(feat + (size_t)c1 * F) + lane * NV;
        float4 av0[NV], bv0[NV], av1[NV], bv1[NV];
#pragma unroll
        for (int k = 0; k < NV; ++k) { av0[k] = a0p[k]; bv0[k] = b0p[k]; av1[k] = a1p[k]; bv1[k] = b1p[k]; }
#pragma unroll
        for (int k = 0; k < NV; ++k) {
            s0 += av0[k].x * bv0[k].x + av0[k].y * bv0[k].y + av0[k].z * bv0[k].z + av0[k].w * bv0[k].w;
            s1 += av1[k].x * bv1[k].x + av1[k].y * bv1[k].y + av1[k].z * bv1[k].z + av1[k].w * bv1[k].w;
        }
    }
#pragma unroll
    for (int off = LPE / 2; off > 0; off >>= 1) {
        s0 += __shfl_xor(s0, off);
        s1 += __shfl_xor(s1, off);
    }
    bool p0 = false, p1 = false;
    if (active && lane == 0) {
        s0 *= inv[r0] * inv[c0];
        if (s0 >= 0.5f && r0 != c0) {
            p0 = true;
            atomicAdd(&rs[r0], s0);
            atomicAdd(&deg[r0], 1.0f);
        }
        if (has1) {
            s1 *= inv[r1] * inv[c1];
            if (s1 >= 0.5f && r1 != c1) {
                p1 = true;
                atomicAdd(&rs[r1], s1);
                atomicAdd(&deg[r1], 1.0f);
            }
        }
    }
    compact_push(p0, (int)e0, s0, wlane, svlist, svs, svcnt);
    compact_push(p1, (int)e1, s1, wlane, svlist, svs, svcnt);
}

// ==================== self weights: ws_self = exp(1/(deg+1)); deg2 init ====================
__global__ void selfw_kernel(const float* __restrict__ deg, float* __restrict__ ws_self,
                             float* __restrict__ deg2, int n) {
    int i = blockIdx.x * TPB + threadIdx.x;
    if (i >= n) return;
    float w = __expf(1.0f / (deg[i] + 1.0f));
    ws_self[i] = w;
    deg2[i] = w;                 // plain init (before survivor atomics)
}

// ==================== survivor weights: svw = exp(svs/rs[row]); deg2[col] += w ====================
__global__ void wsurv_kernel(const int* __restrict__ svlist, const float* __restrict__ svs,
                             float* __restrict__ svw, const float* __restrict__ rs,
                             const int* __restrict__ rowp, const int* __restrict__ colp,
                             float* __restrict__ deg2, const int* __restrict__ svcnt) {
    int S = *svcnt;
    int stride = gridDim.x * TPB;
    for (int i = blockIdx.x * TPB + threadIdx.x; i < S; i += stride) {
        int e = svlist[i];
        float w = __expf(svs[i] / rs[rowp[e]]);
        svw[i] = w;
        atomicAdd(&deg2[colp[e]], w);
    }
}

// ==================== dense h = feat @ W, 128x128: LDS-tiled ====================
__global__ __launch_bounds__(256) void gemm128_kernel(const float* __restrict__ feat,
                                                      const float* __restrict__ W,
                                                      float* __restrict__ out, int n) {
    constexpr int FIN = 128, FOUT = 128, BM = 64;
    __shared__ float Wl[FIN * FOUT];
    __shared__ float Fl[BM * FIN];
    int tid = threadIdx.x;
    int base = blockIdx.x * BM;
    {
        const float4* Wg = (const float4*)W;
        float4* Ws = (float4*)Wl;
        for (int i = tid; i < FIN * FOUT / 4; i += 256) Ws[i] = Wg[i];
    }
    {
        const float4* Fg = (const float4*)(feat + (size_t)base * FIN);
        float4* Fs = (float4*)Fl;
        int maxv = (n - base) * (FIN / 4);
        for (int i = tid; i < BM * FIN / 4; i += 256)
            Fs[i] = (i < maxv) ? Fg[i] : make_float4(0.f, 0.f, 0.f, 0.f);
    }
    __syncthreads();

    int j4 = tid & 31;
    int sub = tid >> 5;
    float4 acc[8];
#pragma unroll
    for (int s = 0; s < 8; ++s) acc[s] = make_float4(0.f, 0.f, 0.f, 0.f);

    for (int k = 0; k < FIN; k += 4) {
        float4 w0 = *(const float4*)&Wl[(k + 0) * FOUT + j4 * 4];
        float4 w1 = *(const float4*)&Wl[(k + 1) * FOUT + j4 * 4];
        float4 w2 = *(const float4*)&Wl[(k + 2) * FOUT + j4 * 4];
        float4 w3 = *(const float4*)&Wl[(k + 3) * FOUT + j4 * 4];
#pragma unroll
        for (int s = 0; s < 8; ++s) {
            float4 f = *(const float4*)&Fl[(sub * 8 + s) * FIN + k];
            acc[s].x += f.x * w0.x + f.y * w1.x + f.z * w2.x + f.w * w3.x;
            acc[s].y += f.x * w0.y + f.y * w1.y + f.z * w2.y + f.w * w3.y;
            acc[s].z += f.x * w0.z + f.y * w1.z + f.z * w2.z + f.w * w3.z;
            acc[s].w += f.x * w0.w + f.y * w1.w + f.z * w2.w + f.w * w3.w;
        }
    }
#pragma unroll
    for (int s = 0; s < 8; ++s) {
        int node = base + sub * 8 + s;
        if (node < n)
            *(float4*)(out + (size_t)node * FOUT + j4 * 4) = acc[s];
    }
}

// ==================== small dense matmul (FIN=16) ====================
template<int FIN, int FOUT, int NPB>
__global__ void matmul_kernel(const float* __restrict__ feat, const float* __restrict__ W,
                              float* __restrict__ out, int n) {
    __shared__ float Wl[FIN * FOUT];
    for (int i = threadIdx.x; i < FIN * FOUT; i += TPB) Wl[i] = W[i];
    __syncthreads();
    constexpr int SLOTS = TPB / FOUT;
    int j = threadIdx.x % FOUT;
    int sub = threadIdx.x / FOUT;
    int base = blockIdx.x * NPB;
    for (int nn = sub; nn < NPB; nn += SLOTS) {
        int node = base + nn;
        if (node >= n) return;
        const float* fr = feat + (size_t)node * FIN;
        float acc = 0.f;
#pragma unroll
        for (int k = 0; k < FIN; ++k) acc += fr[k] * Wl[k * FOUT + j];
        out[(size_t)node * FOUT + j] = acc;
    }
}

// ==================== aggregate over compacted survivors (grid-stride) ====================
template<int F>
__global__ void aggregate_kernel(const float* __restrict__ h, const float* __restrict__ svw,
                                 const float* __restrict__ deg2,
                                 const int* __restrict__ rowp, const int* __restrict__ colp,
                                 const int* __restrict__ svlist, const int* __restrict__ svcnt,
                                 float* __restrict__ out) {
    constexpr int LPE = F / 4;
    long long total = (long long)(*svcnt) * LPE;
    long long stride = (long long)gridDim.x * TPB;
    for (long long idx = (long long)blockIdx.x * TPB + threadIdx.x; idx < total; idx += stride) {
        long long i = idx / LPE;
        int lane = (int)(idx % LPE);
        int e = svlist[i];
        int r = rowp[e], c = colp[e];
        float nw = rsqrtf(deg2[r]) * svw[i] * rsqrtf(deg2[c]);
        const float4 hv = *(const float4*)(h + (size_t)r * F + lane * 4);
        float* op = out + (size_t)c * F + lane * 4;
        atomicAdd(op + 0, nw * hv.x);
        atomicAdd(op + 1, nw * hv.y);
        atomicAdd(op + 2, nw * hv.z);
        atomicAdd(op + 3, nw * hv.w);
    }
}

// ==================== finalize F=128: out = (relu)(agg + (ws_self/deg2)*h + b) ====================
template<bool RELU>
__global__ void finalize128_kernel(float* __restrict__ agg, const float* __restrict__ h,
                                   const float* __restrict__ ws_self, const float* __restrict__ deg2,
                                   const float* __restrict__ b, int n) {
    int gid = blockIdx.x * TPB + threadIdx.x;
    int node = gid >> 5;
    int j4 = gid & 31;
    if (node >= n) return;
    float nw = ws_self[node] / deg2[node];
    float4 hv = *((const float4*)(h + (size_t)node * 128) + j4);
    float4 o  = *((float4*)(agg + (size_t)node * 128) + j4);
    float4 bv = ((const float4*)b)[j4];
    o.x += nw * hv.x + bv.x;
    o.y += nw * hv.y + bv.y;
    o.z += nw * hv.z + bv.z;
    o.w += nw * hv.w + bv.w;
    if (RELU) {
        o.x = fmaxf(o.x, 0.f); o.y = fmaxf(o.y, 0.f);
        o.z = fmaxf(o.z, 0.f); o.w = fmaxf(o.w, 0.f);
    }
    *((float4*)(agg + (size_t)node * 128) + j4) = o;
}

// ==================== finalize F=16, optional relu / log_softmax ====================
template<bool RELU, bool LOGSM>
__global__ void finalize16_kernel(const float* __restrict__ agg, const float* __restrict__ h,
                                  const float* __restrict__ ws_self, const float* __restrict__ deg2,
                                  const float* __restrict__ b, float* __restrict__ out, int n) {
    int node = blockIdx.x * TPB + threadIdx.x;
    if (node >= n) return;
    float nw = ws_self[node] / deg2[node];
    float v[16];
#pragma unroll
    for (int k = 0; k < 4; ++k) {
        float4 a = *((const float4*)(agg + (size_t)node * 16) + k);
        float4 hv = *((const float4*)(h + (size_t)node * 16) + k);
        float4 bv = ((const float4*)b)[k];
        v[4 * k + 0] = a.x + nw * hv.x + bv.x;
        v[4 * k + 1] = a.y + nw * hv.y + bv.y;
        v[4 * k + 2] = a.z + nw * hv.z + bv.z;
        v[4 * k + 3] = a.w + nw * hv.w + bv.w;
    }
    if (RELU) {
#pragma unroll
        for (int k = 0; k < 16; ++k) v[k] = fmaxf(v[k], 0.f);
    }
    if (LOGSM) {
        float m = v[0];
#pragma unroll
        for (int k = 1; k < 16; ++k) m = fmaxf(m, v[k]);
        float s = 0.f;
#pragma unroll
        for (int k = 0; k < 16; ++k) s += expf(v[k] - m);
        float ls = m + logf(s);
#pragma unroll
        for (int k = 0; k < 16; ++k) v[k] -= ls;
    }
#pragma unroll
    for (int k = 0; k < 4; ++k) {
        float4 t = make_float4(v[4 * k], v[4 * k + 1], v[4 * k + 2], v[4 * k + 3]);
        *((float4*)(out + (size_t)node * 16) + k) = t;
    }
}

// =====================================================================
template<int FIN, int FOUT, bool RELU, bool LOGSM>
static void run_layer(const float* feat, const float* W, const float* b,
                      float* h, float* agg, float* fin_out,
                      const int* rowp, const int* colp, int N, long long Er,
                      float* svs, float* svw, float* inv, float* rs, float* deg,
                      float* deg2, float* ws_self, int* svlist, int* svcnt,
                      hipStream_t stream) {
    hipMemsetAsync(rs, 0, sizeof(float) * 2 * (size_t)N, stream);   // rs, deg
    hipMemsetAsync(svcnt, 0, sizeof(int), stream);

    {   // norms
        constexpr int LPN = (FIN >= 64) ? 64 : FIN;
        long long t = (long long)N * LPN;
        norm_kernel<FIN><<<(unsigned)((t + TPB - 1) / TPB), TPB, 0, stream>>>(feat, inv, N);
    }
    {   // edge similarity + survivor compaction
        constexpr int LPE = (FIN >= 128) ? 16 : (FIN / 4);
        long long half = (Er + 1) >> 1;
        long long t = half * LPE;
        sim_kernel<FIN><<<(unsigned)((t + TPB - 1) / TPB), TPB, 0, stream>>>(
            feat, inv, rowp, colp, rs, deg, svlist, svs, svcnt, Er);
    }
    selfw_kernel<<<(unsigned)((N + TPB - 1) / TPB), TPB, 0, stream>>>(deg, ws_self, deg2, N);
    wsurv_kernel<<<1024, TPB, 0, stream>>>(svlist, svs, svw, rs, rowp, colp, deg2, svcnt);

    if (FIN == 128 && FOUT == 128) {
        gemm128_kernel<<<(unsigned)((N + 63) / 64), 256, 0, stream>>>(feat, W, h, N);
    } else {
        matmul_kernel<FIN, FOUT, 64><<<(unsigned)((N + 63) / 64), TPB, 0, stream>>>(feat, W, h, N);
    }

    hipMemsetAsync(agg, 0, sizeof(float) * (size_t)N * FOUT, stream);
    aggregate_kernel<FOUT><<<4096, TPB, 0, stream>>>(h, svw, deg2, rowp, colp, svlist, svcnt, agg);

    if (FOUT == 128) {
        long long t = (long long)N * 32;
        finalize128_kernel<RELU><<<(unsigned)((t + TPB - 1) / TPB), TPB, 0, stream>>>(agg, h, ws_self, deg2, b, N);
    } else {
        finalize16_kernel<RELU, LOGSM><<<(unsigned)((N + TPB - 1) / TPB), TPB, 0, stream>>>(agg, h, ws_self, deg2, b, fin_out, N);
    }
}

extern "C" void kernel_launch(void* const* d_in, const int* in_sizes, int n_in,
                              void* d_out, int out_size, void* d_ws, size_t ws_size,
                              hipStream_t stream) {
    const float* x  = (const float*)d_in[0];
    const int*   row = (const int*)d_in[1];
    const int*   col = (const int*)d_in[2];
    const float* W0 = (const float*)d_in[3];
    const float* b0 = (const float*)d_in[4];
    const float* W1 = (const float*)d_in[5];
    const float* b1 = (const float*)d_in[6];
    const float* W2 = (const float*)d_in[7];
    const float* b2 = (const float*)d_in[8];

    const int NFEAT = 128, NHID = 128;
    int N = in_sizes[0] / NFEAT;            // 50000
    long long E = in_sizes[1];              // 850000 (tail N are self-loops)
    long long Er = E - N;                   // 800000 random edges
    int er = (int)Er;

    float* ws = (float*)d_ws;
    float* A       = ws;                          // [N,128] h
    float* B       = A + (size_t)N * NHID;        // [N,128] feat/agg
    float* svs     = B + (size_t)N * NHID;        // [Er] survivor sims
    float* svw     = svs + Er;                    // [Er] survivor weights
    float* inv     = svw + Er;                    // [N]
    float* rs      = inv + N;                     // [N]
    float* deg     = rs + N;                      // [N]
    float* deg2    = deg + N;                     // [N]
    float* ws_self = deg2 + N;                    // [N]
    int* ip     = (int*)(ws_self + N);
    int* cnt    = ip;                             // [N]
    int* base   = cnt + N;                        // [N]
    int* ptr    = base + N;                       // [N]
    int* bsum   = ptr + N;                        // [256]
    int* rowp   = bsum + 256;                     // [Er]
    int* colp   = rowp + Er;                      // [Er]
    int* svlist = colp + Er;                      // [Er]
    int* svcnt  = svlist + Er;                    // [4]
    float* out  = (float*)d_out;                  // [N,16]

    // ---- sort random edges by row (once; reused by all 3 layers) ----
    int nb = (N + TPB - 1) / TPB;                 // 196 (<=256 required)
    hipMemsetAsync(cnt, 0, sizeof(int) * (size_t)N, stream);
    hist_kernel<<<(er + TPB - 1) / TPB, TPB, 0, stream>>>(row, cnt, er);
    scan1_kernel<<<nb, TPB, 0, stream>>>(cnt, base, bsum, N);
    scan2_kernel<<<1, TPB, 0, stream>>>(bsum, nb);
    scan3_kernel<<<nb, TPB, 0, stream>>>(base, ptr, bsum, N);
    scatter_kernel<<<(er + TPB - 1) / TPB, TPB, 0, stream>>>(row, col, ptr, rowp, colp, er);

    // layer 0: x[N,128] -> B[N,128], relu
    run_layer<128, 128, true,  false>(x, W0, b0, A, B, B,   rowp, colp, N, Er,
                                      svs, svw, inv, rs, deg, deg2, ws_self, svlist, svcnt, stream);
    // layer 1: B[N,128] -> B[N,16], relu
    run_layer<128, 16,  true,  false>(B, W1, b1, A, B, B,   rowp, colp, N, Er,
                                      svs, svw, inv, rs, deg, deg2, ws_self, svlist, svcnt, stream);
    // layer 2: B[N,16] -> out[N,16], log_softmax
    run_layer<16,  16,  false, true >(B, W2, b2, A, B, out, rowp, colp, N, Er,
                                      svs, svw, inv, rs, deg, deg2, ws_self, svlist, svcnt, stream);
}

// Round 6
// 561.602 us; speedup vs baseline: 2.1094x; 2.1094x over previous
//
#include <hip/hip_runtime.h>

static constexpr int TPB = 256;

// ==================== edge sort by row (counting sort) ====================
__global__ void hist_kernel(const int* __restrict__ row, int* __restrict__ cnt, int er) {
    int e = blockIdx.x * TPB + threadIdx.x;
    if (e >= er) return;
    atomicAdd(&cnt[row[e]], 1);
}

__global__ void scan1_kernel(const int* __restrict__ cnt, int* __restrict__ base,
                             int* __restrict__ bsum, int n) {
    __shared__ int s[TPB];
    int g = blockIdx.x * TPB + threadIdx.x;
    int v = (g < n) ? cnt[g] : 0;
    s[threadIdx.x] = v;
    __syncthreads();
    for (int off = 1; off < TPB; off <<= 1) {
        int t = (threadIdx.x >= off) ? s[threadIdx.x - off] : 0;
        __syncthreads();
        s[threadIdx.x] += t;
        __syncthreads();
    }
    if (g < n) base[g] = s[threadIdx.x] - v;            // exclusive
    if (threadIdx.x == TPB - 1) bsum[blockIdx.x] = s[threadIdx.x];
}

__global__ void scan2_kernel(int* __restrict__ bsum, int nb) {
    __shared__ int s[TPB];
    int v = (threadIdx.x < nb) ? bsum[threadIdx.x] : 0;
    s[threadIdx.x] = v;
    __syncthreads();
    for (int off = 1; off < TPB; off <<= 1) {
        int t = (threadIdx.x >= off) ? s[threadIdx.x - off] : 0;
        __syncthreads();
        s[threadIdx.x] += t;
        __syncthreads();
    }
    if (threadIdx.x < nb) bsum[threadIdx.x] = s[threadIdx.x] - v;   // exclusive
}

__global__ void scan3_kernel(const int* __restrict__ base, int* __restrict__ ptr,
                             const int* __restrict__ bsum, int n) {
    int g = blockIdx.x * TPB + threadIdx.x;
    if (g >= n) return;
    ptr[g] = base[g] + bsum[g >> 8];
}

__global__ void scatter_kernel(const int* __restrict__ row, const int* __restrict__ col,
                               int* __restrict__ ptr, int* __restrict__ rowp,
                               int* __restrict__ colp, int er) {
    int e = blockIdx.x * TPB + threadIdx.x;
    if (e >= er) return;
    int r = row[e];
    int p = atomicAdd(&ptr[r], 1);
    rowp[p] = r;
    colp[p] = col[e];
}

// ==================== per-node inverse L2 norm (layer 0 input only) ====================
template<int F>
__global__ void norm_kernel(const float* __restrict__ feat, float* __restrict__ inv, int n) {
    constexpr int LPN = (F >= 64) ? 64 : F;
    constexpr int EPL = F / LPN;
    int gid = blockIdx.x * TPB + threadIdx.x;
    int node = gid / LPN;
    int lane = gid % LPN;
    if (node >= n) return;
    const float* fr = feat + (size_t)node * F;
    float s = 0.f;
#pragma unroll
    for (int k = 0; k < EPL; ++k) {
        float v = fr[lane + k * LPN];
        s += v * v;
    }
#pragma unroll
    for (int off = LPN / 2; off > 0; off >>= 1)
        s += __shfl_xor(s, off);
    if (lane == 0) inv[node] = (s > 0.f) ? rsqrtf(s) : 1.0f;
}

// ==================== edge cosine sim over row-sorted edges (dense write, no compaction) ====================
template<int F>
__global__ void sim_kernel(const float* __restrict__ feat, const float* __restrict__ inv,
                           const int* __restrict__ rowp, const int* __restrict__ colp,
                           float* __restrict__ sim, float* __restrict__ rs, float* __restrict__ deg,
                           long long ne) {
    constexpr int LPE = (F >= 128) ? 16 : (F / 4);
    constexpr int NV  = F / LPE / 4;
    long long half = (ne + 1) >> 1;
    long long gid = (long long)blockIdx.x * TPB + threadIdx.x;
    long long slot = gid / LPE;
    int lane = (int)(gid % LPE);
    if (slot >= half) return;
    long long e0 = slot;
    long long e1 = slot + half;
    bool has1 = (e1 < ne);
    if (!has1) e1 = e0;
    int r0 = rowp[e0], c0 = colp[e0];
    int r1 = rowp[e1], c1 = colp[e1];
    const float4* a0p = (const float4*)(feat + (size_t)r0 * F) + lane * NV;
    const float4* b0p = (const float4*)(feat + (size_t)c0 * F) + lane * NV;
    const float4* a1p = (const float4*)(feat + (size_t)r1 * F) + lane * NV;
    const float4* b1p = (const float4*)(feat + (size_t)c1 * F) + lane * NV;
    float4 av0[NV], bv0[NV], av1[NV], bv1[NV];
#pragma unroll
    for (int k = 0; k < NV; ++k) { av0[k] = a0p[k]; bv0[k] = b0p[k]; av1[k] = a1p[k]; bv1[k] = b1p[k]; }
    float s0 = 0.f, s1 = 0.f;
#pragma unroll
    for (int k = 0; k < NV; ++k) {
        s0 += av0[k].x * bv0[k].x + av0[k].y * bv0[k].y + av0[k].z * bv0[k].z + av0[k].w * bv0[k].w;
        s1 += av1[k].x * bv1[k].x + av1[k].y * bv1[k].y + av1[k].z * bv1[k].z + av1[k].w * bv1[k].w;
    }
#pragma unroll
    for (int off = LPE / 2; off > 0; off >>= 1) {
        s0 += __shfl_xor(s0, off);
        s1 += __shfl_xor(s1, off);
    }
    if (lane == 0) {
        s0 *= inv[r0] * inv[c0];
        if (s0 < 0.5f || r0 == c0) s0 = 0.f;
        sim[e0] = s0;
        if (s0 > 0.f) { atomicAdd(&rs[r0], s0); atomicAdd(&deg[r0], 1.0f); }
        if (has1) {
            s1 *= inv[r1] * inv[c1];
            if (s1 < 0.5f || r1 == c1) s1 = 0.f;
            sim[e1] = s1;
            if (s1 > 0.f) { atomicAdd(&rs[r1], s1); atomicAdd(&deg[r1], 1.0f); }
        }
    }
}

// ==================== fused weights: self weights + edge w=exp(sim/rs); deg2 atomics ====================
// deg2 pre-zeroed by memset. Grid covers Er (>= N).
__global__ void weights_kernel(float* __restrict__ ew, const float* __restrict__ rs,
                               const float* __restrict__ deg,
                               const int* __restrict__ rowp, const int* __restrict__ colp,
                               float* __restrict__ deg2, float* __restrict__ ws_self,
                               long long er, int n) {
    long long e = (long long)blockIdx.x * TPB + threadIdx.x;
    if (e < n) {
        float w = __expf(1.0f / (deg[(int)e] + 1.0f));
        ws_self[(int)e] = w;
        atomicAdd(&deg2[(int)e], w);
    }
    if (e < er) {
        float s = ew[e];
        if (s > 0.f) {
            float w = __expf(s / rs[rowp[e]]);
            ew[e] = w;
            atomicAdd(&deg2[colp[e]], w);
        }
    }
}

// ==================== dense h = feat @ W, 128x128: LDS-tiled ====================
__global__ __launch_bounds__(256) void gemm128_kernel(const float* __restrict__ feat,
                                                      const float* __restrict__ W,
                                                      float* __restrict__ out, int n) {
    constexpr int FIN = 128, FOUT = 128, BM = 64;
    __shared__ float Wl[FIN * FOUT];
    __shared__ float Fl[BM * FIN];
    int tid = threadIdx.x;
    int base = blockIdx.x * BM;
    {
        const float4* Wg = (const float4*)W;
        float4* Ws = (float4*)Wl;
        for (int i = tid; i < FIN * FOUT / 4; i += 256) Ws[i] = Wg[i];
    }
    {
        const float4* Fg = (const float4*)(feat + (size_t)base * FIN);
        float4* Fs = (float4*)Fl;
        int maxv = (n - base) * (FIN / 4);
        for (int i = tid; i < BM * FIN / 4; i += 256)
            Fs[i] = (i < maxv) ? Fg[i] : make_float4(0.f, 0.f, 0.f, 0.f);
    }
    __syncthreads();

    int j4 = tid & 31;
    int sub = tid >> 5;
    float4 acc[8];
#pragma unroll
    for (int s = 0; s < 8; ++s) acc[s] = make_float4(0.f, 0.f, 0.f, 0.f);

    for (int k = 0; k < FIN; k += 4) {
        float4 w0 = *(const float4*)&Wl[(k + 0) * FOUT + j4 * 4];
        float4 w1 = *(const float4*)&Wl[(k + 1) * FOUT + j4 * 4];
        float4 w2 = *(const float4*)&Wl[(k + 2) * FOUT + j4 * 4];
        float4 w3 = *(const float4*)&Wl[(k + 3) * FOUT + j4 * 4];
#pragma unroll
        for (int s = 0; s < 8; ++s) {
            float4 f = *(const float4*)&Fl[(sub * 8 + s) * FIN + k];
            acc[s].x += f.x * w0.x + f.y * w1.x + f.z * w2.x + f.w * w3.x;
            acc[s].y += f.x * w0.y + f.y * w1.y + f.z * w2.y + f.w * w3.y;
            acc[s].z += f.x * w0.z + f.y * w1.z + f.z * w2.z + f.w * w3.z;
            acc[s].w += f.x * w0.w + f.y * w1.w + f.z * w2.w + f.w * w3.w;
        }
    }
#pragma unroll
    for (int s = 0; s < 8; ++s) {
        int node = base + sub * 8 + s;
        if (node < n)
            *(float4*)(out + (size_t)node * FOUT + j4 * 4) = acc[s];
    }
}

// ==================== h = feat @ W for FOUT=16 (4 lanes per node, float4) ====================
template<int FIN>
__global__ void matmulS_kernel(const float* __restrict__ feat, const float* __restrict__ W,
                               float* __restrict__ out, int n) {
    __shared__ float4 Wl[FIN * 4];           // W[k][j4] as float4 over 4 output cols
    for (int i = threadIdx.x; i < FIN * 4; i += TPB) Wl[i] = ((const float4*)W)[i];
    __syncthreads();
    int gid = blockIdx.x * TPB + threadIdx.x;
    int node = gid >> 2;
    int j4 = gid & 3;
    if (node >= n) return;
    const float4* fr = (const float4*)(feat + (size_t)node * FIN);
    float4 acc = make_float4(0.f, 0.f, 0.f, 0.f);
#pragma unroll
    for (int k4 = 0; k4 < FIN / 4; ++k4) {
        float4 f = fr[k4];
        float4 w0 = Wl[(4 * k4 + 0) * 4 + j4];
        float4 w1 = Wl[(4 * k4 + 1) * 4 + j4];
        float4 w2 = Wl[(4 * k4 + 2) * 4 + j4];
        float4 w3 = Wl[(4 * k4 + 3) * 4 + j4];
        acc.x += f.x * w0.x + f.y * w1.x + f.z * w2.x + f.w * w3.x;
        acc.y += f.x * w0.y + f.y * w1.y + f.z * w2.y + f.w * w3.y;
        acc.z += f.x * w0.z + f.y * w1.z + f.z * w2.z + f.w * w3.z;
        acc.w += f.x * w0.w + f.y * w1.w + f.z * w2.w + f.w * w3.w;
    }
    *((float4*)(out + (size_t)node * 16) + j4) = acc;
}

// ==================== aggregate over all edges, early-out on w==0 (grid-stride) ====================
template<int F>
__global__ void aggregate_kernel(const float* __restrict__ h, const float* __restrict__ ew,
                                 const float* __restrict__ deg2,
                                 const int* __restrict__ rowp, const int* __restrict__ colp,
                                 float* __restrict__ out, long long er) {
    constexpr int LPE = F / 4;
    long long total = er * LPE;
    long long stride = (long long)gridDim.x * TPB;
    for (long long idx = (long long)blockIdx.x * TPB + threadIdx.x; idx < total; idx += stride) {
        long long e = idx / LPE;
        int lane = (int)(idx % LPE);
        float we = ew[e];
        if (we == 0.f) continue;
        int r = rowp[e], c = colp[e];
        float nw = rsqrtf(deg2[r]) * we * rsqrtf(deg2[c]);
        const float4 hv = *(const float4*)(h + (size_t)r * F + lane * 4);
        float* op = out + (size_t)c * F + lane * 4;
        atomicAdd(op + 0, nw * hv.x);
        atomicAdd(op + 1, nw * hv.y);
        atomicAdd(op + 2, nw * hv.z);
        atomicAdd(op + 3, nw * hv.w);
    }
}

// ==================== finalize F=128: out=(relu)(agg + (ws_self/deg2)*h + b); writes inv of output ====================
template<bool RELU>
__global__ void finalize128_kernel(float* __restrict__ agg, const float* __restrict__ h,
                                   const float* __restrict__ ws_self, const float* __restrict__ deg2,
                                   const float* __restrict__ b, float* __restrict__ inv, int n) {
    int gid = blockIdx.x * TPB + threadIdx.x;
    int node = gid >> 5;
    int j4 = gid & 31;
    if (node >= n) return;
    float nw = ws_self[node] / deg2[node];
    float4 hv = *((const float4*)(h + (size_t)node * 128) + j4);
    float4 o  = *((float4*)(agg + (size_t)node * 128) + j4);
    float4 bv = ((const float4*)b)[j4];
    o.x += nw * hv.x + bv.x;
    o.y += nw * hv.y + bv.y;
    o.z += nw * hv.z + bv.z;
    o.w += nw * hv.w + bv.w;
    if (RELU) {
        o.x = fmaxf(o.x, 0.f); o.y = fmaxf(o.y, 0.f);
        o.z = fmaxf(o.z, 0.f); o.w = fmaxf(o.w, 0.f);
    }
    *((float4*)(agg + (size_t)node * 128) + j4) = o;
    // inverse L2 norm of the 128-dim output row (32 lanes per node, width-32 butterfly)
    float ss = o.x * o.x + o.y * o.y + o.z * o.z + o.w * o.w;
#pragma unroll
    for (int off = 16; off > 0; off >>= 1)
        ss += __shfl_xor(ss, off, 32);
    if (j4 == 0) inv[node] = (ss > 0.f) ? rsqrtf(ss) : 1.0f;
}

// ==================== finalize F=16, optional relu / log_softmax / inv-write ====================
template<bool RELU, bool LOGSM, bool WINV>
__global__ void finalize16_kernel(const float* __restrict__ agg, const float* __restrict__ h,
                                  const float* __restrict__ ws_self, const float* __restrict__ deg2,
                                  const float* __restrict__ b, float* __restrict__ out,
                                  float* __restrict__ inv, int n) {
    int node = blockIdx.x * TPB + threadIdx.x;
    if (node >= n) return;
    float nw = ws_self[node] / deg2[node];
    float v[16];
#pragma unroll
    for (int k = 0; k < 4; ++k) {
        float4 a = *((const float4*)(agg + (size_t)node * 16) + k);
        float4 hv = *((const float4*)(h + (size_t)node * 16) + k);
        float4 bv = ((const float4*)b)[k];
        v[4 * k + 0] = a.x + nw * hv.x + bv.x;
        v[4 * k + 1] = a.y + nw * hv.y + bv.y;
        v[4 * k + 2] = a.z + nw * hv.z + bv.z;
        v[4 * k + 3] = a.w + nw * hv.w + bv.w;
    }
    if (RELU) {
#pragma unroll
        for (int k = 0; k < 16; ++k) v[k] = fmaxf(v[k], 0.f);
    }
    if (WINV) {
        float ss = 0.f;
#pragma unroll
        for (int k = 0; k < 16; ++k) ss += v[k] * v[k];
        inv[node] = (ss > 0.f) ? rsqrtf(ss) : 1.0f;
    }
    if (LOGSM) {
        float m = v[0];
#pragma unroll
        for (int k = 1; k < 16; ++k) m = fmaxf(m, v[k]);
        float s = 0.f;
#pragma unroll
        for (int k = 0; k < 16; ++k) s += expf(v[k] - m);
        float ls = m + logf(s);
#pragma unroll
        for (int k = 0; k < 16; ++k) v[k] -= ls;
    }
#pragma unroll
    for (int k = 0; k < 4; ++k) {
        float4 t = make_float4(v[4 * k], v[4 * k + 1], v[4 * k + 2], v[4 * k + 3]);
        *((float4*)(out + (size_t)node * 16) + k) = t;
    }
}

// =====================================================================
template<int FIN, int FOUT, bool RELU, bool LOGSM, bool WINV>
static void run_layer(const float* feat, const float* W, const float* b,
                      float* h, float* agg, float* fin_out,
                      const int* rowp, const int* colp, int N, long long Er,
                      float* ew, float* inv, float* rs, float* deg, float* deg2, float* ws_self,
                      hipStream_t stream) {
    hipMemsetAsync(rs, 0, sizeof(float) * 3 * (size_t)N, stream);   // rs, deg, deg2 contiguous

    {   // edge similarity (2 edges per thread), dense sim write into ew
        constexpr int LPE = (FIN >= 128) ? 16 : (FIN / 4);
        long long half = (Er + 1) >> 1;
        long long t = half * LPE;
        sim_kernel<FIN><<<(unsigned)((t + TPB - 1) / TPB), TPB, 0, stream>>>(
            feat, inv, rowp, colp, ew, rs, deg, Er);
    }
    weights_kernel<<<(unsigned)((Er + TPB - 1) / TPB), TPB, 0, stream>>>(
        ew, rs, deg, rowp, colp, deg2, ws_self, Er, N);

    if (FIN == 128 && FOUT == 128) {
        gemm128_kernel<<<(unsigned)((N + 63) / 64), 256, 0, stream>>>(feat, W, h, N);
    } else {
        matmulS_kernel<FIN><<<(unsigned)(((long long)N * 4 + TPB - 1) / TPB), TPB, 0, stream>>>(feat, W, h, N);
    }

    hipMemsetAsync(agg, 0, sizeof(float) * (size_t)N * FOUT, stream);
    aggregate_kernel<FOUT><<<2048, TPB, 0, stream>>>(h, ew, deg2, rowp, colp, agg, Er);

    if (FOUT == 128) {
        long long t = (long long)N * 32;
        finalize128_kernel<RELU><<<(unsigned)((t + TPB - 1) / TPB), TPB, 0, stream>>>(
            agg, h, ws_self, deg2, b, inv, N);
    } else {
        finalize16_kernel<RELU, LOGSM, WINV><<<(unsigned)((N + TPB - 1) / TPB), TPB, 0, stream>>>(
            agg, h, ws_self, deg2, b, fin_out, inv, N);
    }
}

extern "C" void kernel_launch(void* const* d_in, const int* in_sizes, int n_in,
                              void* d_out, int out_size, void* d_ws, size_t ws_size,
                              hipStream_t stream) {
    const float* x  = (const float*)d_in[0];
    const int*   row = (const int*)d_in[1];
    const int*   col = (const int*)d_in[2];
    const float* W0 = (const float*)d_in[3];
    const float* b0 = (const float*)d_in[4];
    const float* W1 = (const float*)d_in[5];
    const float* b1 = (const float*)d_in[6];
    const float* W2 = (const float*)d_in[7];
    const float* b2 = (const float*)d_in[8];

    const int NFEAT = 128, NHID = 128;
    int N = in_sizes[0] / NFEAT;            // 50000
    long long E = in_sizes[1];              // 850000 (tail N are self-loops)
    long long Er = E - N;                   // 800000 random edges
    int er = (int)Er;

    float* ws = (float*)d_ws;
    float* A       = ws;                          // [N,128] h
    float* B       = A + (size_t)N * NHID;        // [N,128] feat/agg
    float* ew      = B + (size_t)N * NHID;        // [Er] sim -> w (dense)
    float* inv     = ew + Er;                     // [N]
    float* rs      = inv + N;                     // [N]
    float* deg     = rs + N;                      // [N]  (rs,deg,deg2 contiguous for memset)
    float* deg2    = deg + N;                     // [N]
    float* ws_self = deg2 + N;                    // [N]
    int* cnt    = (int*)(ws_self + N);            // [N]
    int* base   = cnt + N;                        // [N]
    int* ptr    = base + N;                       // [N]
    int* bsum   = ptr + N;                        // [256]
    int* rowp   = bsum + 256;                     // [Er]
    int* colp   = rowp + Er;                      // [Er]
    float* out  = (float*)d_out;                  // [N,16]

    // ---- sort random edges by row (once; reused by all 3 layers) ----
    int nb = (N + TPB - 1) / TPB;                 // 196 (<=256 required)
    hipMemsetAsync(cnt, 0, sizeof(int) * (size_t)N, stream);
    hist_kernel<<<(er + TPB - 1) / TPB, TPB, 0, stream>>>(row, cnt, er);
    scan1_kernel<<<nb, TPB, 0, stream>>>(cnt, base, bsum, N);
    scan2_kernel<<<1, TPB, 0, stream>>>(bsum, nb);
    scan3_kernel<<<nb, TPB, 0, stream>>>(base, ptr, bsum, N);
    scatter_kernel<<<(er + TPB - 1) / TPB, TPB, 0, stream>>>(row, col, ptr, rowp, colp, er);

    // layer-0 input norms
    norm_kernel<128><<<(unsigned)(((long long)N * 64 + TPB - 1) / TPB), TPB, 0, stream>>>(x, inv, N);

    // layer 0: x[N,128] -> B[N,128], relu (finalize writes inv for layer 1)
    run_layer<128, 128, true,  false, true >(x, W0, b0, A, B, B,   rowp, colp, N, Er,
                                             ew, inv, rs, deg, deg2, ws_self, stream);
    // layer 1: B[N,128] -> B[N,16], relu (finalize writes inv for layer 2)
    run_layer<128, 16,  true,  false, true >(B, W1, b1, A, B, B,   rowp, colp, N, Er,
                                             ew, inv, rs, deg, deg2, ws_self, stream);
    // layer 2: B[N,16] -> out[N,16], log_softmax
    run_layer<16,  16,  false, true,  false>(B, W2, b2, A, B, out, rowp, colp, N, Er,
                                             ew, inv, rs, deg, deg2, ws_self, stream);
}

// Round 7
// 427.845 us; speedup vs baseline: 2.7689x; 1.3126x over previous
//
#include <hip/hip_runtime.h>

static constexpr int TPB = 256;

// ==================== edge sort by COL (counting sort) -> col-CSR ====================
__global__ void hist_kernel(const int* __restrict__ col, int* __restrict__ cnt, int er) {
    int e = blockIdx.x * TPB + threadIdx.x;
    if (e >= er) return;
    atomicAdd(&cnt[col[e]], 1);
}

__global__ void scan1_kernel(const int* __restrict__ cnt, int* __restrict__ base,
                             int* __restrict__ bsum, int n) {
    __shared__ int s[TPB];
    int g = blockIdx.x * TPB + threadIdx.x;
    int v = (g < n) ? cnt[g] : 0;
    s[threadIdx.x] = v;
    __syncthreads();
    for (int off = 1; off < TPB; off <<= 1) {
        int t = (threadIdx.x >= off) ? s[threadIdx.x - off] : 0;
        __syncthreads();
        s[threadIdx.x] += t;
        __syncthreads();
    }
    if (g < n) base[g] = s[threadIdx.x] - v;            // exclusive (per-chunk)
    if (threadIdx.x == TPB - 1) bsum[blockIdx.x] = s[threadIdx.x];
}

__global__ void scan2_kernel(int* __restrict__ bsum, int nb) {
    __shared__ int s[TPB];
    int v = (threadIdx.x < nb) ? bsum[threadIdx.x] : 0;
    s[threadIdx.x] = v;
    __syncthreads();
    for (int off = 1; off < TPB; off <<= 1) {
        int t = (threadIdx.x >= off) ? s[threadIdx.x - off] : 0;
        __syncthreads();
        s[threadIdx.x] += t;
        __syncthreads();
    }
    if (threadIdx.x < nb) bsum[threadIdx.x] = s[threadIdx.x] - v;   // exclusive
}

// writes global start offsets into BOTH base (kept) and ptr (mutated by scatter -> end)
__global__ void scan3_kernel(int* __restrict__ base, int* __restrict__ ptr,
                             const int* __restrict__ bsum, int n) {
    int g = blockIdx.x * TPB + threadIdx.x;
    if (g >= n) return;
    int b = base[g] + bsum[g >> 8];
    base[g] = b;
    ptr[g] = b;
}

__global__ void scatter_kernel(const int* __restrict__ row, const int* __restrict__ col,
                               int* __restrict__ ptr, int* __restrict__ rowp,
                               int* __restrict__ colp, int er) {
    int e = blockIdx.x * TPB + threadIdx.x;
    if (e >= er) return;
    int c = col[e];
    int p = atomicAdd(&ptr[c], 1);
    rowp[p] = row[e];
    colp[p] = c;
}

// ==================== per-node inverse L2 norm (layer-0 input only) ====================
template<int F>
__global__ void norm_kernel(const float* __restrict__ feat, float* __restrict__ inv, int n) {
    constexpr int LPN = (F >= 64) ? 64 : F;
    constexpr int EPL = F / LPN;
    int gid = blockIdx.x * TPB + threadIdx.x;
    int node = gid / LPN;
    int lane = gid % LPN;
    if (node >= n) return;
    const float* fr = feat + (size_t)node * F;
    float s = 0.f;
#pragma unroll
    for (int k = 0; k < EPL; ++k) {
        float v = fr[lane + k * LPN];
        s += v * v;
    }
#pragma unroll
    for (int off = LPN / 2; off > 0; off >>= 1)
        s += __shfl_xor(s, off);
    if (lane == 0) inv[node] = (s > 0.f) ? rsqrtf(s) : 1.0f;
}

// ==================== edge cosine sim over col-sorted edges (dense write) ====================
template<int F>
__global__ void sim_kernel(const float* __restrict__ feat, const float* __restrict__ inv,
                           const int* __restrict__ rowp, const int* __restrict__ colp,
                           float* __restrict__ sim, float* __restrict__ rs, float* __restrict__ deg,
                           long long ne) {
    constexpr int LPE = (F >= 128) ? 16 : (F / 4);
    constexpr int NV  = F / LPE / 4;
    long long half = (ne + 1) >> 1;
    long long gid = (long long)blockIdx.x * TPB + threadIdx.x;
    long long slot = gid / LPE;
    int lane = (int)(gid % LPE);
    if (slot >= half) return;
    long long e0 = slot;
    long long e1 = slot + half;
    bool has1 = (e1 < ne);
    if (!has1) e1 = e0;
    int r0 = rowp[e0], c0 = colp[e0];
    int r1 = rowp[e1], c1 = colp[e1];
    const float4* a0p = (const float4*)(feat + (size_t)r0 * F) + lane * NV;
    const float4* b0p = (const float4*)(feat + (size_t)c0 * F) + lane * NV;
    const float4* a1p = (const float4*)(feat + (size_t)r1 * F) + lane * NV;
    const float4* b1p = (const float4*)(feat + (size_t)c1 * F) + lane * NV;
    float4 av0[NV], bv0[NV], av1[NV], bv1[NV];
#pragma unroll
    for (int k = 0; k < NV; ++k) { av0[k] = a0p[k]; bv0[k] = b0p[k]; av1[k] = a1p[k]; bv1[k] = b1p[k]; }
    float s0 = 0.f, s1 = 0.f;
#pragma unroll
    for (int k = 0; k < NV; ++k) {
        s0 += av0[k].x * bv0[k].x + av0[k].y * bv0[k].y + av0[k].z * bv0[k].z + av0[k].w * bv0[k].w;
        s1 += av1[k].x * bv1[k].x + av1[k].y * bv1[k].y + av1[k].z * bv1[k].z + av1[k].w * bv1[k].w;
    }
#pragma unroll
    for (int off = LPE / 2; off > 0; off >>= 1) {
        s0 += __shfl_xor(s0, off);
        s1 += __shfl_xor(s1, off);
    }
    if (lane == 0) {
        s0 *= inv[r0] * inv[c0];
        if (s0 < 0.5f || r0 == c0) s0 = 0.f;
        sim[e0] = s0;
        if (s0 > 0.f) { atomicAdd(&rs[r0], s0); atomicAdd(&deg[r0], 1.0f); }
        if (has1) {
            s1 *= inv[r1] * inv[c1];
            if (s1 < 0.5f || r1 == c1) s1 = 0.f;
            sim[e1] = s1;
            if (s1 > 0.f) { atomicAdd(&rs[r1], s1); atomicAdd(&deg[r1], 1.0f); }
        }
    }
}

// ==================== col-segmented: w=exp(sim/rs[row]) in place; deg2[c]=ws_self+Σw (no atomics) ====================
__global__ void wdeg2_kernel(float* __restrict__ ew, const float* __restrict__ rs,
                             const float* __restrict__ deg, const int* __restrict__ rowp,
                             const int* __restrict__ base, const int* __restrict__ endp,
                             float* __restrict__ deg2, float* __restrict__ ws_self, int n) {
    int gid = blockIdx.x * TPB + threadIdx.x;
    int c = gid >> 2;
    int l = gid & 3;
    if (c >= n) return;
    int s = base[c], e_end = endp[c];
    float sum = 0.f;
    for (int e = s + l; e < e_end; e += 4) {
        float sv = ew[e];
        if (sv > 0.f) {
            float w = __expf(sv / rs[rowp[e]]);
            ew[e] = w;
            sum += w;
        }
    }
    sum += __shfl_xor(sum, 1, 4);
    sum += __shfl_xor(sum, 2, 4);
    if (l == 0) {
        float wsf = __expf(1.0f / (deg[c] + 1.0f));
        ws_self[c] = wsf;
        deg2[c] = wsf + sum;
    }
}

// ==================== dense h = feat @ W, 128x128: LDS-tiled ====================
__global__ __launch_bounds__(256) void gemm128_kernel(const float* __restrict__ feat,
                                                      const float* __restrict__ W,
                                                      float* __restrict__ out, int n) {
    constexpr int FIN = 128, FOUT = 128, BM = 64;
    __shared__ float Wl[FIN * FOUT];
    __shared__ float Fl[BM * FIN];
    int tid = threadIdx.x;
    int base = blockIdx.x * BM;
    {
        const float4* Wg = (const float4*)W;
        float4* Ws = (float4*)Wl;
        for (int i = tid; i < FIN * FOUT / 4; i += 256) Ws[i] = Wg[i];
    }
    {
        const float4* Fg = (const float4*)(feat + (size_t)base * FIN);
        float4* Fs = (float4*)Fl;
        int maxv = (n - base) * (FIN / 4);
        for (int i = tid; i < BM * FIN / 4; i += 256)
            Fs[i] = (i < maxv) ? Fg[i] : make_float4(0.f, 0.f, 0.f, 0.f);
    }
    __syncthreads();

    int j4 = tid & 31;
    int sub = tid >> 5;
    float4 acc[8];
#pragma unroll
    for (int s = 0; s < 8; ++s) acc[s] = make_float4(0.f, 0.f, 0.f, 0.f);

    for (int k = 0; k < FIN; k += 4) {
        float4 w0 = *(const float4*)&Wl[(k + 0) * FOUT + j4 * 4];
        float4 w1 = *(const float4*)&Wl[(k + 1) * FOUT + j4 * 4];
        float4 w2 = *(const float4*)&Wl[(k + 2) * FOUT + j4 * 4];
        float4 w3 = *(const float4*)&Wl[(k + 3) * FOUT + j4 * 4];
#pragma unroll
        for (int s = 0; s < 8; ++s) {
            float4 f = *(const float4*)&Fl[(sub * 8 + s) * FIN + k];
            acc[s].x += f.x * w0.x + f.y * w1.x + f.z * w2.x + f.w * w3.x;
            acc[s].y += f.x * w0.y + f.y * w1.y + f.z * w2.y + f.w * w3.y;
            acc[s].z += f.x * w0.z + f.y * w1.z + f.z * w2.z + f.w * w3.z;
            acc[s].w += f.x * w0.w + f.y * w1.w + f.z * w2.w + f.w * w3.w;
        }
    }
#pragma unroll
    for (int s = 0; s < 8; ++s) {
        int node = base + sub * 8 + s;
        if (node < n)
            *(float4*)(out + (size_t)node * FOUT + j4 * 4) = acc[s];
    }
}

// ==================== h = feat @ W for FOUT=16 (4 lanes per node, float4) ====================
template<int FIN>
__global__ void matmulS_kernel(const float* __restrict__ feat, const float* __restrict__ W,
                               float* __restrict__ out, int n) {
    __shared__ float4 Wl[FIN * 4];
    for (int i = threadIdx.x; i < FIN * 4; i += TPB) Wl[i] = ((const float4*)W)[i];
    __syncthreads();
    int gid = blockIdx.x * TPB + threadIdx.x;
    int node = gid >> 2;
    int j4 = gid & 3;
    if (node >= n) return;
    const float4* fr = (const float4*)(feat + (size_t)node * FIN);
    float4 acc = make_float4(0.f, 0.f, 0.f, 0.f);
#pragma unroll
    for (int k4 = 0; k4 < FIN / 4; ++k4) {
        float4 f = fr[k4];
        float4 w0 = Wl[(4 * k4 + 0) * 4 + j4];
        float4 w1 = Wl[(4 * k4 + 1) * 4 + j4];
        float4 w2 = Wl[(4 * k4 + 2) * 4 + j4];
        float4 w3 = Wl[(4 * k4 + 3) * 4 + j4];
        acc.x += f.x * w0.x + f.y * w1.x + f.z * w2.x + f.w * w3.x;
        acc.y += f.x * w0.y + f.y * w1.y + f.z * w2.y + f.w * w3.y;
        acc.z += f.x * w0.z + f.y * w1.z + f.z * w2.z + f.w * w3.z;
        acc.w += f.x * w0.w + f.y * w1.w + f.z * w2.w + f.w * w3.w;
    }
    *((float4*)(out + (size_t)node * 16) + j4) = acc;
}

// ==================== fused segmented aggregate + finalize, F=128 (32 lanes/col) ====================
template<bool RELU>
__global__ void aggfin128_kernel(const float* __restrict__ h, const float* __restrict__ ew,
                                 const float* __restrict__ deg2, const int* __restrict__ rowp,
                                 const int* __restrict__ base, const int* __restrict__ endp,
                                 const float* __restrict__ ws_self, const float* __restrict__ b,
                                 float* __restrict__ outb, float* __restrict__ inv, int n) {
    int gid = blockIdx.x * TPB + threadIdx.x;
    int c = gid >> 5;
    int j4 = gid & 31;
    if (c >= n) return;
    int s = base[c], e_end = endp[c];
    float d2c = deg2[c];
    float dc = rsqrtf(d2c);
    float4 acc = make_float4(0.f, 0.f, 0.f, 0.f);
    for (int e = s; e < e_end; ++e) {
        float we = ew[e];
        if (we == 0.f) continue;
        int r = rowp[e];
        float nw = rsqrtf(deg2[r]) * we * dc;
        float4 hv = *((const float4*)(h + (size_t)r * 128) + j4);
        acc.x += nw * hv.x; acc.y += nw * hv.y; acc.z += nw * hv.z; acc.w += nw * hv.w;
    }
    float nws = ws_self[c] / d2c;
    float4 hv = *((const float4*)(h + (size_t)c * 128) + j4);
    float4 bv = ((const float4*)b)[j4];
    float4 o;
    o.x = acc.x + nws * hv.x + bv.x;
    o.y = acc.y + nws * hv.y + bv.y;
    o.z = acc.z + nws * hv.z + bv.z;
    o.w = acc.w + nws * hv.w + bv.w;
    if (RELU) {
        o.x = fmaxf(o.x, 0.f); o.y = fmaxf(o.y, 0.f);
        o.z = fmaxf(o.z, 0.f); o.w = fmaxf(o.w, 0.f);
    }
    *((float4*)(outb + (size_t)c * 128) + j4) = o;
    // inverse L2 norm of output row (width-32 butterfly) for next layer's sim
    float ss = o.x * o.x + o.y * o.y + o.z * o.z + o.w * o.w;
#pragma unroll
    for (int off = 16; off > 0; off >>= 1)
        ss += __shfl_xor(ss, off, 32);
    if (j4 == 0) inv[c] = (ss > 0.f) ? rsqrtf(ss) : 1.0f;
}

// ==================== fused segmented aggregate + finalize, F=16 (4 lanes/col) ====================
template<bool RELU, bool LOGSM, bool WINV>
__global__ void aggfin16_kernel(const float* __restrict__ h, const float* __restrict__ ew,
                                const float* __restrict__ deg2, const int* __restrict__ rowp,
                                const int* __restrict__ base, const int* __restrict__ endp,
                                const float* __restrict__ ws_self, const float* __restrict__ b,
                                float* __restrict__ out, float* __restrict__ inv, int n) {
    int gid = blockIdx.x * TPB + threadIdx.x;
    int c = gid >> 2;
    int l = gid & 3;
    if (c >= n) return;
    int s = base[c], e_end = endp[c];
    float d2c = deg2[c];
    float dc = rsqrtf(d2c);
    float4 acc = make_float4(0.f, 0.f, 0.f, 0.f);
    for (int e = s; e < e_end; ++e) {
        float we = ew[e];
        if (we == 0.f) continue;
        int r = rowp[e];
        float nw = rsqrtf(deg2[r]) * we * dc;
        float4 hv = *((const float4*)(h + (size_t)r * 16) + l);
        acc.x += nw * hv.x; acc.y += nw * hv.y; acc.z += nw * hv.z; acc.w += nw * hv.w;
    }
    float nws = ws_self[c] / d2c;
    float4 hv = *((const float4*)(h + (size_t)c * 16) + l);
    float4 bv = ((const float4*)b)[l];
    float4 v;
    v.x = acc.x + nws * hv.x + bv.x;
    v.y = acc.y + nws * hv.y + bv.y;
    v.z = acc.z + nws * hv.z + bv.z;
    v.w = acc.w + nws * hv.w + bv.w;
    if (RELU) {
        v.x = fmaxf(v.x, 0.f); v.y = fmaxf(v.y, 0.f);
        v.z = fmaxf(v.z, 0.f); v.w = fmaxf(v.w, 0.f);
    }
    if (WINV) {
        float ss = v.x * v.x + v.y * v.y + v.z * v.z + v.w * v.w;
        ss += __shfl_xor(ss, 1, 4);
        ss += __shfl_xor(ss, 2, 4);
        if (l == 0) inv[c] = (ss > 0.f) ? rsqrtf(ss) : 1.0f;
    }
    if (LOGSM) {
        float m = fmaxf(fmaxf(v.x, v.y), fmaxf(v.z, v.w));
        m = fmaxf(m, __shfl_xor(m, 1, 4));
        m = fmaxf(m, __shfl_xor(m, 2, 4));
        float sm = expf(v.x - m) + expf(v.y - m) + expf(v.z - m) + expf(v.w - m);
        sm += __shfl_xor(sm, 1, 4);
        sm += __shfl_xor(sm, 2, 4);
        float ls = m + logf(sm);
        v.x -= ls; v.y -= ls; v.z -= ls; v.w -= ls;
    }
    *((float4*)(out + (size_t)c * 16) + l) = v;
}

// =====================================================================
template<int FIN, int FOUT, bool RELU, bool LOGSM, bool WINV>
static void run_layer(const float* feat, const float* W, const float* b,
                      float* h, float* fin_out,
                      const int* rowp, const int* colp, const int* basep, const int* endp,
                      int N, long long Er,
                      float* ew, float* inv, float* rs, float* deg, float* deg2, float* ws_self,
                      hipStream_t stream) {
    hipMemsetAsync(rs, 0, sizeof(float) * 2 * (size_t)N, stream);   // rs, deg contiguous

    {   // edge similarity (2 edges per thread), dense sim write into ew
        constexpr int LPE = (FIN >= 128) ? 16 : (FIN / 4);
        long long half = (Er + 1) >> 1;
        long long t = half * LPE;
        sim_kernel<FIN><<<(unsigned)((t + TPB - 1) / TPB), TPB, 0, stream>>>(
            feat, inv, rowp, colp, ew, rs, deg, Er);
    }
    wdeg2_kernel<<<(unsigned)(((long long)N * 4 + TPB - 1) / TPB), TPB, 0, stream>>>(
        ew, rs, deg, rowp, basep, endp, deg2, ws_self, N);

    if (FIN == 128 && FOUT == 128) {
        gemm128_kernel<<<(unsigned)((N + 63) / 64), 256, 0, stream>>>(feat, W, h, N);
    } else {
        matmulS_kernel<FIN><<<(unsigned)(((long long)N * 4 + TPB - 1) / TPB), TPB, 0, stream>>>(feat, W, h, N);
    }

    if (FOUT == 128) {
        long long t = (long long)N * 32;
        aggfin128_kernel<RELU><<<(unsigned)((t + TPB - 1) / TPB), TPB, 0, stream>>>(
            h, ew, deg2, rowp, basep, endp, ws_self, b, fin_out, inv, N);
    } else {
        long long t = (long long)N * 4;
        aggfin16_kernel<RELU, LOGSM, WINV><<<(unsigned)((t + TPB - 1) / TPB), TPB, 0, stream>>>(
            h, ew, deg2, rowp, basep, endp, ws_self, b, fin_out, inv, N);
    }
}

extern "C" void kernel_launch(void* const* d_in, const int* in_sizes, int n_in,
                              void* d_out, int out_size, void* d_ws, size_t ws_size,
                              hipStream_t stream) {
    const float* x  = (const float*)d_in[0];
    const int*   row = (const int*)d_in[1];
    const int*   col = (const int*)d_in[2];
    const float* W0 = (const float*)d_in[3];
    const float* b0 = (const float*)d_in[4];
    const float* W1 = (const float*)d_in[5];
    const float* b1 = (const float*)d_in[6];
    const float* W2 = (const float*)d_in[7];
    const float* b2 = (const float*)d_in[8];

    const int NFEAT = 128, NHID = 128;
    int N = in_sizes[0] / NFEAT;            // 50000
    long long E = in_sizes[1];              // 850000 (tail N are self-loops)
    long long Er = E - N;                   // 800000 random edges
    int er = (int)Er;

    float* ws = (float*)d_ws;
    float* A       = ws;                          // [N,128] h
    float* B       = A + (size_t)N * NHID;        // [N,128] feat buffer
    float* ew      = B + (size_t)N * NHID;        // [Er] sim -> w (dense, col-sorted order)
    float* inv     = ew + Er;                     // [N]
    float* rs      = inv + N;                     // [N]
    float* deg     = rs + N;                      // [N]  (rs,deg contiguous for memset)
    float* deg2    = deg + N;                     // [N]
    float* ws_self = deg2 + N;                    // [N]
    int* cnt    = (int*)(ws_self + N);            // [N]
    int* base   = cnt + N;                        // [N] segment starts (col-CSR)
    int* ptr    = base + N;                       // [N] scatter cursor -> segment ends
    int* bsum   = ptr + N;                        // [256]
    int* rowp   = bsum + 256;                     // [Er] row of col-sorted edges
    int* colp   = rowp + Er;                      // [Er] col of col-sorted edges
    float* out  = (float*)d_out;                  // [N,16]

    // ---- sort random edges by col (once; reused by all 3 layers) ----
    int nb = (N + TPB - 1) / TPB;                 // 196 (<=256 required)
    hipMemsetAsync(cnt, 0, sizeof(int) * (size_t)N, stream);
    hist_kernel<<<(er + TPB - 1) / TPB, TPB, 0, stream>>>(col, cnt, er);
    scan1_kernel<<<nb, TPB, 0, stream>>>(cnt, base, bsum, N);
    scan2_kernel<<<1, TPB, 0, stream>>>(bsum, nb);
    scan3_kernel<<<nb, TPB, 0, stream>>>(base, ptr, bsum, N);
    scatter_kernel<<<(er + TPB - 1) / TPB, TPB, 0, stream>>>(row, col, ptr, rowp, colp, er);
    // after scatter: base[c] = segment start, ptr[c] = segment end

    // layer-0 input norms
    norm_kernel<128><<<(unsigned)(((long long)N * 64 + TPB - 1) / TPB), TPB, 0, stream>>>(x, inv, N);

    // layer 0: x[N,128] -> B[N,128], relu (aggfin writes inv for layer 1)
    run_layer<128, 128, true,  false, true >(x, W0, b0, A, B,   rowp, colp, base, ptr, N, Er,
                                             ew, inv, rs, deg, deg2, ws_self, stream);
    // layer 1: B[N,128] -> B[N,16], relu (aggfin writes inv for layer 2; h in A)
    run_layer<128, 16,  true,  false, true >(B, W1, b1, A, B,   rowp, colp, base, ptr, N, Er,
                                             ew, inv, rs, deg, deg2, ws_self, stream);
    // layer 2: B[N,16] -> out[N,16], log_softmax
    run_layer<16,  16,  false, true,  false>(B, W2, b2, A, out, rowp, colp, base, ptr, N, Er,
                                             ew, inv, rs, deg, deg2, ws_self, stream);
}